// Round 7
// baseline (804.216 us; speedup 1.0000x reference)
//
#include <hip/hip_runtime.h>

#define N_ 16
#define C_ 256
#define H_ 128
#define W_ 128
#define O_ 256
#define HW_ (H_ * W_)
#define CHW_ (C_ * HW_)
#define WELEMS (O_ * C_ * 9)   // 589824
#define WB_WORDS 73728         // 2(oh)*8(cch)*9(kk)*2(wm)*16(l15)*4(g)*4(mi) 16-bit words

// ---- padded bf16 x layout: xb[n][h' 0..129][cg 0..7][w' 0..129][32c]
// 64B line; halo zero; 16B sub-chunks pre-permuted (slot j holds c-sub
// j ^ ((w'>>1)&3)) so linear global_load_lds + swizzled ds_read = conflict-free.
#define XH 130
#define XW 130
#define XB_LINE 64
#define XB_BYTES ((long)N_ * XH * 8 * XW * XB_LINE)   // 138,444,800
#define XB_OFF (2l << 20)
#define WS_NEED (XB_OFF + XB_BYTES)

#define ROWB 4224            // 66 points * 64 B per staged row
#define BUFB (6 * ROWB)      // 25344 B per buffer

typedef short bf16x8 __attribute__((ext_vector_type(8)));
typedef float f32x4 __attribute__((ext_vector_type(4)));

#define GLOAD_LDS16(g, l)                                                     \
  __builtin_amdgcn_global_load_lds(                                           \
      (const __attribute__((address_space(1))) unsigned int*)(g),             \
      (__attribute__((address_space(3))) unsigned int*)(l), 16, 0, 0)

__global__ void absum_k(const float* __restrict__ w, float* __restrict__ sum) {
  int tid = blockIdx.x * blockDim.x + threadIdx.x;
  float s = 0.f;
  for (int i = tid; i < WELEMS; i += gridDim.x * blockDim.x) s += fabsf(w[i]);
  #pragma unroll
  for (int off = 32; off > 0; off >>= 1) s += __shfl_down(s, off, 64);
  if ((threadIdx.x & 63) == 0) atomicAdd(sum, s);
}

// ternary 2-bit pack: word i covers 8 c's for (ohalf,cch,kk,wm,l15,g,mi).
// field: 0 -> 0.0, 1 -> +1.0, 2 -> -1.0
__global__ void quant_k(const float* __restrict__ w, const float* __restrict__ sum,
                        unsigned short* __restrict__ wb) {
  int i = blockIdx.x * 256 + threadIdx.x;
  if (i >= WB_WORDS) return;
  float scale = fmaxf(sum[0] * (1.0f / (float)WELEMS), 1e-5f);
  const int mi = i & 3, g = (i >> 2) & 3, l15 = (i >> 4) & 15, wm = (i >> 8) & 1;
  const int kk = (i >> 9) % 9, t2 = (i >> 9) / 9, cch = t2 & 7, ohalf = t2 >> 3;
  const int o = ohalf * 128 + wm * 64 + mi * 16 + l15;
  const int ky = kk / 3, kx = kk - ky * 3;
  unsigned int word = 0;
  #pragma unroll
  for (int j = 0; j < 8; ++j) {
    const int c = cch * 32 + g * 8 + j;
    float q = rintf(w[((o * C_ + c) * 3 + ky) * 3 + kx] / scale);
    q = fminf(1.f, fmaxf(-1.f, q));
    unsigned int f = (q > 0.5f) ? 1u : (q < -0.5f ? 2u : 0u);
    word |= f << (2 * j);
  }
  wb[i] = (unsigned short)word;
}

// zero the halo lines of xb
__global__ void halo_k(unsigned char* __restrict__ xbb) {
  int i = blockIdx.x * 256 + threadIdx.x;
  if (i >= 66560) return;
  long line;
  if (i < 33280) {
    int wq = i % 130; int t = i / 130;
    int cg = t & 7; t >>= 3;
    int hh = t & 1; int nn = t >> 1;
    line = (((long)nn * XH + hh * 129) * 8 + cg) * XW + wq;
  } else {
    int j = i - 33280;
    int side = j & 1; int t = j >> 1;
    int cg = t & 7; t >>= 3;
    int hp = t % 130; int nn = t / 130;
    line = (((long)nn * XH + hp) * 8 + cg) * XW + side * 129;
  }
  f32x4 z = (f32x4){0.f, 0.f, 0.f, 0.f};
  #pragma unroll
  for (int j4 = 0; j4 < 4; ++j4)
    *(f32x4*)(xbb + line * XB_LINE + j4 * 16) = z;
}

// x NCHW f32 -> xb. Nontemporal x reads (read-once stream, keep L3 for xb).
__global__ void xform_k(const float* __restrict__ x, unsigned char* __restrict__ xbb) {
  const int b = blockIdx.x;
  const int wh = b & 1, h = (b >> 1) & 127, n = b >> 8;
  const int t = threadIdx.x;
  const int wl = t & 63, q = t >> 6;
  const int w = (wh << 6) + wl;
  const float* s0 = x + ((long)n * C_ + q * 64) * HW_ + h * W_ + w;
  const int mw = ((w + 1) >> 1) & 3;
  const long lbase = (((long)n * XH + (h + 1)) * 8) * XW + (w + 1);
  #pragma unroll
  for (int sub = 0; sub < 4; ++sub) {
    float v[16];
    #pragma unroll
    for (int k = 0; k < 16; ++k)
      v[k] = __builtin_nontemporal_load(&s0[(long)(sub * 16 + k) * HW_]);
    bf16x8 p0, p1;
    #pragma unroll
    for (int k = 0; k < 8; ++k) {
      p0[k] = (short)__builtin_bit_cast(unsigned short, (__bf16)v[k]);
      p1[k] = (short)__builtin_bit_cast(unsigned short, (__bf16)v[8 + k]);
    }
    const int cg = q * 2 + (sub >> 1);
    const int j0 = (sub & 1) * 2;
    unsigned char* lp = xbb + (lbase + (long)cg * XW) * XB_LINE;
    *(bf16x8*)(lp + ((j0) ^ mw) * 16) = p0;
    *(bf16x8*)(lp + ((j0 + 1) ^ mw) * 16) = p1;
  }
}

// ---- conv: 128 o x [4 rows x 64 w] per block, 512 thr (8 waves: 2 o x 4 rows).
// 3 LDS buffers, counted vmcnt, one raw barrier per chunk, 2-bit A expand.
__global__ void __launch_bounds__(512, 4)
conv_k(const unsigned char* __restrict__ xbb,
       const float* __restrict__ bias,
       const unsigned char* __restrict__ wbb,
       const float* __restrict__ sum,
       float* __restrict__ out) {
  __shared__ __attribute__((aligned(128))) unsigned char Xs[3][BUFB];

  const int swz = (blockIdx.x & 7) * 256 + (blockIdx.x >> 3);
  const int pid = swz >> 2, sub = swz & 3;
  const int ohalf = sub >> 1, wblk = sub & 1;
  const int n = pid >> 5;
  const int h0 = (pid & 31) << 2;
  const int w0 = wblk << 6;
  const int o_blk = ohalf << 7;

  const int tid = threadIdx.x;
  const int wid = tid >> 6, lane = tid & 63;
  const int l15 = lane & 15, g = lane >> 4;
  const int wmd = (wid >> 2);              // wave o-half within 128: 0/1 (o + 64*wmd)
  const int r = wid & 3;                   // wave output row 0..3

  f32x4 acc[4][4];
  #pragma unroll
  for (int i = 0; i < 4; ++i)
    #pragma unroll
    for (int j = 0; j < 4; ++j) acc[i][j] = (f32x4){0.f, 0.f, 0.f, 0.f};

  // per-lane weight-bit base: layout [ohalf][cch][kk][wm][l15][g][mi] * 2B
  const unsigned char* wlb0 =
      wbb + ((long)ohalf * 8) * 9 * 1024 + wmd * 512 + (l15 * 4 + g) * 8;

  // waves 0..5 each stage one input row (66 lines x 64B)
  auto stage = [&](int b, int cg) {
    if (wid < 6) {
      const unsigned char* src =
          xbb + ((((long)n * XH + h0 + wid) * 8 + cg) * XW + w0) * XB_LINE;
      unsigned char* dst = &Xs[b][wid * ROWB];
      #pragma unroll
      for (int it = 0; it < 4; ++it)
        GLOAD_LDS16(src + (it * 64 + lane) * 16, dst + it * 1024);
      if (lane < 8)
        GLOAD_LDS16(src + (256 + lane) * 16, dst + 4096);
    }
  };

  auto expand = [&](unsigned int m) -> bf16x8 {
    bf16x8 e;
    #pragma unroll
    for (int j = 0; j < 8; ++j) {
      unsigned int f = (m >> (2 * j)) & 3u;
      e[j] = (short)(f == 1u ? 0x3F80 : (f == 2u ? 0xBF80 : 0));
    }
    return e;
  };

  auto compute = [&](const unsigned char* Xb, int cch) {
    const unsigned char* wlb = wlb0 + (long)cch * 9 * 1024;
    uint2 wcur = *(const uint2*)(wlb);
    #pragma unroll
    for (int kk = 0; kk < 9; ++kk) {
      uint2 wnxt;
      if (kk < 8) wnxt = *(const uint2*)(wlb + (kk + 1) * 1024);
      const int ky = kk / 3, kx = kk - ky * 3;
      const int li = r + ky;
      bf16x8 bb[4];
      #pragma unroll
      for (int ni = 0; ni < 4; ++ni) {
        const int wq = (ni << 4) + l15 + kx;
        const int s = g ^ ((wq >> 1) & 3);
        bb[ni] = *(const bf16x8*)(Xb + li * ROWB + wq * 64 + s * 16);
      }
      __builtin_amdgcn_s_setprio(1);
      #pragma unroll
      for (int mi = 0; mi < 4; ++mi) {
        unsigned int mh;
        if (mi == 0) mh = wcur.x & 0xFFFFu;
        else if (mi == 1) mh = wcur.x >> 16;
        else if (mi == 2) mh = wcur.y & 0xFFFFu;
        else mh = wcur.y >> 16;
        const bf16x8 a = expand(mh);
        #pragma unroll
        for (int ni = 0; ni < 4; ++ni)
          acc[mi][ni] = __builtin_amdgcn_mfma_f32_16x16x32_bf16(a, bb[ni], acc[mi][ni], 0, 0, 0);
      }
      __builtin_amdgcn_s_setprio(0);
      wcur = wnxt;
    }
  };

  stage(0, 0);
  stage(1, 1);
  #pragma unroll
  for (int t = 0; t < 8; ++t) {
    __builtin_amdgcn_sched_barrier(0);
    if (t < 7) { asm volatile("s_waitcnt vmcnt(5)" ::: "memory"); }
    else       { asm volatile("s_waitcnt vmcnt(0)" ::: "memory"); }
    __builtin_amdgcn_s_barrier();
    __builtin_amdgcn_sched_barrier(0);
    compute(Xs[t % 3], t);
    __builtin_amdgcn_sched_barrier(0);
    if (t < 6) stage((t + 2) % 3, t + 2);
  }

  // epilogue: nontemporal out-stores (don't pollute L2/L3)
  const float scale = fmaxf(sum[0] * (1.0f / (float)WELEMS), 1e-5f);
  const int h_out = h0 + r;
  #pragma unroll
  for (int mi = 0; mi < 4; ++mi) {
    #pragma unroll
    for (int q = 0; q < 4; ++q) {
      const int o = o_blk + wmd * 64 + (mi << 4) + (g << 2) + q;
      const float bv = bias[o];
      float* orow = out + ((long)n * O_ + o) * (long)HW_ + h_out * W_;
      #pragma unroll
      for (int ni = 0; ni < 4; ++ni) {
        const int wc = w0 + (ni << 4) + l15;
        __builtin_nontemporal_store(acc[mi][ni][q] * scale + bv, &orow[wc]);
      }
    }
  }
}

// ================= fallback (ws too small): simple 2-phase, 2-bit weights ===
#define LSTRIDE 80
#define LINES_FB 130
__global__ void __launch_bounds__(512, 4)
conv_fb(const float* __restrict__ x,
        const float* __restrict__ bias,
        const unsigned char* __restrict__ wbb,
        const float* __restrict__ sum,
        float* __restrict__ out) {
  __shared__ __attribute__((aligned(128))) unsigned char Xs[4 * 130 * LSTRIDE];
  const int bid = blockIdx.x;
  const int pid = bid >> 1, ohalf = bid & 1;
  const int spid = (pid & 7) * 128 + (pid >> 3);
  const int n = spid >> 6;
  const int h0 = (spid & 63) << 1;
  const int o_blk = ohalf << 7;
  const int tid = threadIdx.x;
  if (tid < 128) {
    const int li = tid >> 5, sel = (tid >> 4) & 1, word = tid & 15;
    const int wq = sel ? 129 : 0;
    *(int*)(Xs + (li * LINES_FB + wq) * LSTRIDE + word * 4) = 0;
  }
  const int wid = tid >> 6, lane = tid & 63;
  const int l15 = lane & 15, g = lane >> 4;
  const int wmd = wid >> 2;
  const int wsid = wid & 3, r = wsid >> 1, wbase = (wsid & 1) << 6;
  const int sw = tid & 127, sli = tid >> 7;
  const int h_in = h0 - 1 + sli;
  const bool inb = (unsigned)h_in < (unsigned)H_;
  const float* xsrc = x + (long)n * CHW_ + (long)h_in * W_ + sw;
  unsigned char* sdst = Xs + (sli * LINES_FB + sw + 1) * LSTRIDE;
  const unsigned char* wlb0 =
      wbb + ((long)ohalf * 8) * 9 * 1024 + wmd * 512 + (l15 * 4 + g) * 8;
  f32x4 acc[4][4];
  #pragma unroll
  for (int i = 0; i < 4; ++i)
    #pragma unroll
    for (int j = 0; j < 4; ++j) acc[i][j] = (f32x4){0.f, 0.f, 0.f, 0.f};
  for (int c0 = 0; c0 < C_; c0 += 32) {
    #pragma unroll
    for (int cg = 0; cg < 4; ++cg) {
      bf16x8 pk = (bf16x8){0, 0, 0, 0, 0, 0, 0, 0};
      if (inb) {
        const float* s = xsrc + (long)(c0 + (cg << 3)) * HW_;
        #pragma unroll
        for (int k = 0; k < 8; ++k)
          pk[k] = (short)__builtin_bit_cast(unsigned short, (__bf16)s[(long)k * HW_]);
      }
      *(bf16x8*)(sdst + (cg << 4)) = pk;
    }
    __syncthreads();
    const unsigned char* wlb = wlb0 + (long)(c0 >> 5) * 9 * 1024;
    #pragma unroll
    for (int kk = 0; kk < 9; ++kk) {
      const int ky = kk / 3, kx = kk - ky * 3;
      const int li = r + ky;
      const uint2 wc2 = *(const uint2*)(wlb + kk * 1024);
      #pragma unroll
      for (int mi = 0; mi < 4; ++mi) {
        unsigned int mh;
        if (mi == 0) mh = wc2.x & 0xFFFFu;
        else if (mi == 1) mh = wc2.x >> 16;
        else if (mi == 2) mh = wc2.y & 0xFFFFu;
        else mh = wc2.y >> 16;
        bf16x8 a;
        #pragma unroll
        for (int j = 0; j < 8; ++j) {
          unsigned int f = (mh >> (2 * j)) & 3u;
          a[j] = (short)(f == 1u ? 0x3F80 : (f == 2u ? 0xBF80 : 0));
        }
        #pragma unroll
        for (int ni = 0; ni < 4; ++ni) {
          const int wq = wbase + (ni << 4) + l15 + kx;
          const bf16x8 bb = *(const bf16x8*)(&Xs[(li * LINES_FB + wq) * LSTRIDE + (g << 4)]);
          acc[mi][ni] = __builtin_amdgcn_mfma_f32_16x16x32_bf16(a, bb, acc[mi][ni], 0, 0, 0);
        }
      }
    }
    __syncthreads();
  }
  const float scale = fmaxf(sum[0] * (1.0f / (float)WELEMS), 1e-5f);
  const int h_out = h0 + r;
  #pragma unroll
  for (int mi = 0; mi < 4; ++mi) {
    #pragma unroll
    for (int q = 0; q < 4; ++q) {
      const int o = o_blk + wmd * 64 + (mi << 4) + (g << 2) + q;
      const float bv = bias[o];
      float* orow = out + ((long)n * O_ + o) * (long)HW_ + h_out * W_;
      #pragma unroll
      for (int ni = 0; ni < 4; ++ni) {
        const int wc = wbase + (ni << 4) + l15;
        orow[wc] = acc[mi][ni][q] * scale + bv;
      }
    }
  }
}

extern "C" void kernel_launch(void* const* d_in, const int* in_sizes, int n_in,
                              void* d_out, int out_size, void* d_ws, size_t ws_size,
                              hipStream_t stream) {
  const float* x = (const float*)d_in[0];
  const float* w = (const float*)d_in[1];
  const float* bias = (const float*)d_in[2];
  float* out = (float*)d_out;
  float* sum = (float*)d_ws;
  unsigned short* wb = (unsigned short*)((char*)d_ws + 64);

  hipMemsetAsync(d_ws, 0, 4, stream);
  absum_k<<<256, 256, 0, stream>>>(w, sum);
  quant_k<<<WB_WORDS / 256, 256, 0, stream>>>(w, sum, wb);

  if (ws_size >= (size_t)WS_NEED) {
    unsigned char* xbb = (unsigned char*)d_ws + XB_OFF;
    halo_k<<<260, 256, 0, stream>>>(xbb);
    xform_k<<<4096, 256, 0, stream>>>(x, xbb);
    conv_k<<<2048, 512, 0, stream>>>(xbb, bias, (const unsigned char*)wb, sum, out);
  } else {
    conv_fb<<<2048, 512, 0, stream>>>(x, bias, (const unsigned char*)wb, sum, out);
  }
}

// Round 8
// 799.913 us; speedup vs baseline: 1.0054x; 1.0054x over previous
//
#include <hip/hip_runtime.h>

#define N_ 16
#define C_ 256
#define H_ 128
#define W_ 128
#define O_ 256
#define HW_ (H_ * W_)
#define CHW_ (C_ * HW_)
#define WELEMS (O_ * C_ * 9)   // 589824

// ---- padded bf16 x layout: xb[n][h' 0..129][cg 0..7][w' 0..129][32c]
// 64B line; halo zero; 16B sub-chunks pre-permuted (slot j holds c-sub
// j ^ ((w'>>1)&3)) so linear global_load_lds + swizzled ds_read = conflict-free.
#define XH 130
#define XW 130
#define XB_LINE 64
#define XB_BYTES ((long)N_ * XH * 8 * XW * XB_LINE)   // 138,444,800
#define XB_OFF (2l << 20)
#define WS_NEED (XB_OFF + XB_BYTES)

#define ROWB 4224            // 66 points * 64 B per staged row
#define BUFB (6 * ROWB)      // 25344 B per buffer

typedef short bf16x8 __attribute__((ext_vector_type(8)));
typedef float f32x4 __attribute__((ext_vector_type(4)));

#define GLOAD_LDS16(g, l)                                                     \
  __builtin_amdgcn_global_load_lds(                                           \
      (const __attribute__((address_space(1))) unsigned int*)(g),             \
      (__attribute__((address_space(3))) unsigned int*)(l), 16, 0, 0)

__global__ void absum_k(const float* __restrict__ w, float* __restrict__ sum) {
  int tid = blockIdx.x * blockDim.x + threadIdx.x;
  float s = 0.f;
  for (int i = tid; i < WELEMS; i += gridDim.x * blockDim.x) s += fabsf(w[i]);
  #pragma unroll
  for (int off = 32; off > 0; off >>= 1) s += __shfl_down(s, off, 64);
  if ((threadIdx.x & 63) == 0) atomicAdd(sum, s);
}

// bf16 ternary weights: wp[(kk*O + o)*C + c] = {-1,0,+1} (scale in epilogue)
__global__ void quant_k(const float* __restrict__ w, const float* __restrict__ sum,
                        unsigned short* __restrict__ wp) {
  int i = blockIdx.x * blockDim.x + threadIdx.x;
  if (i >= WELEMS) return;
  float scale = fmaxf(sum[0] * (1.0f / (float)WELEMS), 1e-5f);
  int kk = i % 9;              // ky*3+kx
  int c = (i / 9) % C_;
  int o = i / (9 * C_);
  float q = rintf(w[i] / scale);
  q = fminf(1.f, fmaxf(-1.f, q));
  wp[(kk * O_ + o) * C_ + c] = __builtin_bit_cast(unsigned short, (__bf16)q);
}

// zero the halo lines of xb
__global__ void halo_k(unsigned char* __restrict__ xbb) {
  int i = blockIdx.x * 256 + threadIdx.x;
  if (i >= 66560) return;
  long line;
  if (i < 33280) {
    int wq = i % 130; int t = i / 130;
    int cg = t & 7; t >>= 3;
    int hh = t & 1; int nn = t >> 1;
    line = (((long)nn * XH + hh * 129) * 8 + cg) * XW + wq;
  } else {
    int j = i - 33280;
    int side = j & 1; int t = j >> 1;
    int cg = t & 7; t >>= 3;
    int hp = t % 130; int nn = t / 130;
    line = (((long)nn * XH + hp) * 8 + cg) * XW + side * 129;
  }
  f32x4 z = (f32x4){0.f, 0.f, 0.f, 0.f};
  #pragma unroll
  for (int j4 = 0; j4 < 4; ++j4)
    *(f32x4*)(xbb + line * XB_LINE + j4 * 16) = z;
}

// x NCHW f32 -> xb. Nontemporal x reads (read-once stream, keep L2/L3 for xb+wp).
__global__ void xform_k(const float* __restrict__ x, unsigned char* __restrict__ xbb) {
  const int b = blockIdx.x;
  const int wh = b & 1, h = (b >> 1) & 127, n = b >> 8;
  const int t = threadIdx.x;
  const int wl = t & 63, q = t >> 6;
  const int w = (wh << 6) + wl;
  const float* s0 = x + ((long)n * C_ + q * 64) * HW_ + h * W_ + w;
  const int mw = ((w + 1) >> 1) & 3;
  const long lbase = (((long)n * XH + (h + 1)) * 8) * XW + (w + 1);
  #pragma unroll
  for (int sub = 0; sub < 4; ++sub) {
    float v[16];
    #pragma unroll
    for (int k = 0; k < 16; ++k)
      v[k] = __builtin_nontemporal_load(&s0[(long)(sub * 16 + k) * HW_]);
    bf16x8 p0, p1;
    #pragma unroll
    for (int k = 0; k < 8; ++k) {
      p0[k] = (short)__builtin_bit_cast(unsigned short, (__bf16)v[k]);
      p1[k] = (short)__builtin_bit_cast(unsigned short, (__bf16)v[8 + k]);
    }
    const int cg = q * 2 + (sub >> 1);
    const int j0 = (sub & 1) * 2;
    unsigned char* lp = xbb + (lbase + (long)cg * XW) * XB_LINE;
    *(bf16x8*)(lp + ((j0) ^ mw) * 16) = p0;
    *(bf16x8*)(lp + ((j0 + 1) ^ mw) * 16) = p1;
  }
}

// ---- conv: 128 o x [4 rows x 64 w] per block, 512 thr (8 waves: 2 o x 4 rows).
// 3 LDS buffers, counted vmcnt, one raw barrier per chunk; bf16 A from L2.
__global__ void __launch_bounds__(512, 4)
conv_k(const unsigned char* __restrict__ xbb,
       const float* __restrict__ bias,
       const unsigned short* __restrict__ wp,
       const float* __restrict__ sum,
       float* __restrict__ out) {
  __shared__ __attribute__((aligned(128))) unsigned char Xs[3][BUFB];

  const int swz = (blockIdx.x & 7) * 256 + (blockIdx.x >> 3);
  const int pid = swz >> 2, sub = swz & 3;
  const int ohalf = sub >> 1, wblk = sub & 1;
  const int n = pid >> 5;
  const int h0 = (pid & 31) << 2;
  const int w0 = wblk << 6;
  const int o_blk = ohalf << 7;

  const int tid = threadIdx.x;
  const int wid = tid >> 6, lane = tid & 63;
  const int l15 = lane & 15, g = lane >> 4;
  const int wmd = (wid >> 2);              // wave o-half within 128: 0/1
  const int r = wid & 3;                   // wave output row 0..3

  f32x4 acc[4][4];
  #pragma unroll
  for (int i = 0; i < 4; ++i)
    #pragma unroll
    for (int j = 0; j < 4; ++j) acc[i][j] = (f32x4){0.f, 0.f, 0.f, 0.f};

  // waves 0..5 each stage one input row (66 lines x 64B)
  auto stage = [&](int b, int cg) {
    if (wid < 6) {
      const unsigned char* src =
          xbb + ((((long)n * XH + h0 + wid) * 8 + cg) * XW + w0) * XB_LINE;
      unsigned char* dst = &Xs[b][wid * ROWB];
      #pragma unroll
      for (int it = 0; it < 4; ++it)
        GLOAD_LDS16(src + (it * 64 + lane) * 16, dst + it * 1024);
      if (lane < 8)
        GLOAD_LDS16(src + (256 + lane) * 16, dst + 4096);
    }
  };

  auto compute = [&](const unsigned char* Xb, int c0) {
    #pragma unroll
    for (int kk = 0; kk < 9; ++kk) {
      const int ky = kk / 3, kx = kk - ky * 3;
      const int li = r + ky;
      const unsigned short* abase =
          wp + ((kk * O_ + o_blk + wmd * 64 + l15) * C_) + c0 + (g << 3);
      bf16x8 a0 = *(const bf16x8*)(abase);
      bf16x8 a1 = *(const bf16x8*)(abase + 16 * C_);
      bf16x8 a2 = *(const bf16x8*)(abase + 32 * C_);
      bf16x8 a3 = *(const bf16x8*)(abase + 48 * C_);
      bf16x8 bb[4];
      #pragma unroll
      for (int ni = 0; ni < 4; ++ni) {
        const int wq = (ni << 4) + l15 + kx;
        const int s = g ^ ((wq >> 1) & 3);
        bb[ni] = *(const bf16x8*)(Xb + li * ROWB + wq * 64 + s * 16);
      }
      __builtin_amdgcn_s_setprio(1);
      #pragma unroll
      for (int ni = 0; ni < 4; ++ni) {
        acc[0][ni] = __builtin_amdgcn_mfma_f32_16x16x32_bf16(a0, bb[ni], acc[0][ni], 0, 0, 0);
        acc[1][ni] = __builtin_amdgcn_mfma_f32_16x16x32_bf16(a1, bb[ni], acc[1][ni], 0, 0, 0);
        acc[2][ni] = __builtin_amdgcn_mfma_f32_16x16x32_bf16(a2, bb[ni], acc[2][ni], 0, 0, 0);
        acc[3][ni] = __builtin_amdgcn_mfma_f32_16x16x32_bf16(a3, bb[ni], acc[3][ni], 0, 0, 0);
      }
      __builtin_amdgcn_s_setprio(0);
    }
  };

  stage(0, 0);
  stage(1, 1);
  #pragma unroll
  for (int t = 0; t < 8; ++t) {
    __builtin_amdgcn_sched_barrier(0);
    if (t < 7) { asm volatile("s_waitcnt vmcnt(5)" ::: "memory"); }
    else       { asm volatile("s_waitcnt vmcnt(0)" ::: "memory"); }
    __builtin_amdgcn_s_barrier();
    __builtin_amdgcn_sched_barrier(0);
    compute(Xs[t % 3], t << 5);
    __builtin_amdgcn_sched_barrier(0);
    if (t < 6) stage((t + 2) % 3, t + 2);
  }

  // epilogue: nontemporal out-stores (don't pollute L2/L3)
  const float scale = fmaxf(sum[0] * (1.0f / (float)WELEMS), 1e-5f);
  const int h_out = h0 + r;
  #pragma unroll
  for (int mi = 0; mi < 4; ++mi) {
    #pragma unroll
    for (int q = 0; q < 4; ++q) {
      const int o = o_blk + wmd * 64 + (mi << 4) + (g << 2) + q;
      const float bv = bias[o];
      float* orow = out + ((long)n * O_ + o) * (long)HW_ + h_out * W_;
      #pragma unroll
      for (int ni = 0; ni < 4; ++ni) {
        const int wc = w0 + (ni << 4) + l15;
        __builtin_nontemporal_store(acc[mi][ni][q] * scale + bv, &orow[wc]);
      }
    }
  }
}

// ================= fallback (ws too small): R2-style 2-phase ===============
#define LSTRIDE 80
#define LINES_FB 130
__global__ void __launch_bounds__(512, 4)
conv_fb(const float* __restrict__ x,
        const float* __restrict__ bias,
        const unsigned short* __restrict__ wp,
        const float* __restrict__ sum,
        float* __restrict__ out) {
  __shared__ __attribute__((aligned(128))) unsigned char Xs[4 * 130 * LSTRIDE];
  const int bid = blockIdx.x;
  const int pid = bid >> 1, ohalf = bid & 1;
  const int spid = (pid & 7) * 128 + (pid >> 3);
  const int n = spid >> 6;
  const int h0 = (spid & 63) << 1;
  const int o_blk = ohalf << 7;
  const int tid = threadIdx.x;
  if (tid < 128) {
    const int li = tid >> 5, sel = (tid >> 4) & 1, word = tid & 15;
    const int wq = sel ? 129 : 0;
    *(int*)(Xs + (li * LINES_FB + wq) * LSTRIDE + word * 4) = 0;
  }
  const int wid = tid >> 6, lane = tid & 63;
  const int l15 = lane & 15, g = lane >> 4;
  const int wmo = (wid >> 2) << 6;
  const int wsid = wid & 3, r = wsid >> 1, wbase = (wsid & 1) << 6;
  const int sw = tid & 127, sli = tid >> 7;
  const int h_in = h0 - 1 + sli;
  const bool inb = (unsigned)h_in < (unsigned)H_;
  const float* xsrc = x + (long)n * CHW_ + (long)h_in * W_ + sw;
  unsigned char* sdst = Xs + (sli * LINES_FB + sw + 1) * LSTRIDE;
  f32x4 acc[4][4];
  #pragma unroll
  for (int i = 0; i < 4; ++i)
    #pragma unroll
    for (int j = 0; j < 4; ++j) acc[i][j] = (f32x4){0.f, 0.f, 0.f, 0.f};
  for (int c0 = 0; c0 < C_; c0 += 32) {
    #pragma unroll
    for (int cg = 0; cg < 4; ++cg) {
      bf16x8 pk = (bf16x8){0, 0, 0, 0, 0, 0, 0, 0};
      if (inb) {
        const float* s = xsrc + (long)(c0 + (cg << 3)) * HW_;
        #pragma unroll
        for (int k = 0; k < 8; ++k)
          pk[k] = (short)__builtin_bit_cast(unsigned short, (__bf16)s[(long)k * HW_]);
      }
      *(bf16x8*)(sdst + (cg << 4)) = pk;
    }
    __syncthreads();
    #pragma unroll
    for (int kk = 0; kk < 9; ++kk) {
      const int ky = kk / 3, kx = kk - ky * 3;
      const int li = r + ky;
      const unsigned short* abase =
          wp + ((kk * O_ + o_blk + wmo + l15) * C_) + c0 + (g << 3);
      bf16x8 a[4];
      #pragma unroll
      for (int mi = 0; mi < 4; ++mi)
        a[mi] = *(const bf16x8*)(abase + (mi << 4) * C_);
      #pragma unroll
      for (int ni = 0; ni < 4; ++ni) {
        const int wq = wbase + (ni << 4) + l15 + kx;
        const bf16x8 bb = *(const bf16x8*)(&Xs[(li * LINES_FB + wq) * LSTRIDE + (g << 4)]);
        #pragma unroll
        for (int mi = 0; mi < 4; ++mi)
          acc[mi][ni] = __builtin_amdgcn_mfma_f32_16x16x32_bf16(a[mi], bb, acc[mi][ni], 0, 0, 0);
      }
    }
    __syncthreads();
  }
  const float scale = fmaxf(sum[0] * (1.0f / (float)WELEMS), 1e-5f);
  const int h_out = h0 + r;
  #pragma unroll
  for (int mi = 0; mi < 4; ++mi) {
    #pragma unroll
    for (int q = 0; q < 4; ++q) {
      const int o = o_blk + wmo + (mi << 4) + (g << 2) + q;
      const float bv = bias[o];
      float* orow = out + ((long)n * O_ + o) * (long)HW_ + h_out * W_;
      #pragma unroll
      for (int ni = 0; ni < 4; ++ni) {
        const int wc = wbase + (ni << 4) + l15;
        orow[wc] = acc[mi][ni][q] * scale + bv;
      }
    }
  }
}

extern "C" void kernel_launch(void* const* d_in, const int* in_sizes, int n_in,
                              void* d_out, int out_size, void* d_ws, size_t ws_size,
                              hipStream_t stream) {
  const float* x = (const float*)d_in[0];
  const float* w = (const float*)d_in[1];
  const float* bias = (const float*)d_in[2];
  float* out = (float*)d_out;
  float* sum = (float*)d_ws;
  unsigned short* wp = (unsigned short*)((char*)d_ws + 64);

  hipMemsetAsync(d_ws, 0, 4, stream);
  absum_k<<<256, 256, 0, stream>>>(w, sum);
  quant_k<<<WELEMS / 256, 256, 0, stream>>>(w, sum, wp);

  if (ws_size >= (size_t)WS_NEED) {
    unsigned char* xbb = (unsigned char*)d_ws + XB_OFF;
    halo_k<<<260, 256, 0, stream>>>(xbb);
    xform_k<<<4096, 256, 0, stream>>>(x, xbb);
    conv_k<<<2048, 512, 0, stream>>>(xbb, bias, wp, sum, out);
  } else {
    conv_fb<<<2048, 512, 0, stream>>>(x, bias, wp, sum, out);
  }
}